// Round 9
// baseline (15.591 us; speedup 1.0000x reference)
//
#include <hip/hip_runtime.h>
#include <math.h>

#define NPTS 2048
#define KDIM 400

typedef float f32x4 __attribute__((ext_vector_type(4)));

// Kernel 1: blocks 0..127 = FF (2 per batch row, split-K + 4-way accum ILP);
//           blocks 128..255 = kval, 16 pts/block, thread = (f, slot, pt).
__global__ __launch_bounds__(512) void k_ff_and_kval(
    const float* __restrict__ weights, const float* __restrict__ grid,
    const float* __restrict__ ff_w1, const float* __restrict__ ff_b1,
    const float* __restrict__ ff_w2, const float* __restrict__ ff_b2,
    const float* __restrict__ ff_w3, const float* __restrict__ ff_b3,
    const float* __restrict__ k_w1, const float* __restrict__ k_b1,
    const float* __restrict__ k_w2, const float* __restrict__ k_b2,
    const float* __restrict__ k_w3, const float* __restrict__ k_b3,
    float* __restrict__ integ, float4* __restrict__ kvp)
{
    const int t = threadIdx.x;
    if (blockIdx.x < 128) {
        // ---- FeedForward: block pair (b, half), split-K + 4 accumulators ----
        const int b = blockIdx.x >> 1, half = blockIdx.x & 1;
        __shared__ float wrow[256], h1[120], h2[240];
        __shared__ float p1[4][120], p2[2][240], p3[2][200];

        if (t < 256) wrow[t] = weights[b * 256 + t];
        __syncthreads();

        if (t < 480) {           // layer 1: 120 outs, 4-way split-K (64 each)
            const int seg = t / 120, o = t - seg * 120;
            const int i0 = seg * 64;
            float s0 = (seg == 0) ? ff_b1[o] : 0.f, s1 = 0.f, s2 = 0.f, s3 = 0.f;
            #pragma unroll
            for (int i = 0; i < 64; i += 4) {
                s0 = fmaf(wrow[i0+i+0], ff_w1[(i0+i+0) * 120 + o], s0);
                s1 = fmaf(wrow[i0+i+1], ff_w1[(i0+i+1) * 120 + o], s1);
                s2 = fmaf(wrow[i0+i+2], ff_w1[(i0+i+2) * 120 + o], s2);
                s3 = fmaf(wrow[i0+i+3], ff_w1[(i0+i+3) * 120 + o], s3);
            }
            p1[seg][o] = (s0 + s1) + (s2 + s3);
        }
        __syncthreads();
        if (t < 120) h1[t] = tanhf(p1[0][t] + p1[1][t] + p1[2][t] + p1[3][t]);
        __syncthreads();

        if (t < 480) {           // layer 2: 240 outs, 2-way split-K (60 each)
            const int seg = t / 240, o = t - seg * 240;
            const int i0 = seg * 60;
            float s0 = (seg == 0) ? ff_b2[o] : 0.f, s1 = 0.f, s2 = 0.f, s3 = 0.f;
            #pragma unroll
            for (int i = 0; i < 60; i += 4) {
                s0 = fmaf(h1[i0+i+0], ff_w2[(i0+i+0) * 240 + o], s0);
                s1 = fmaf(h1[i0+i+1], ff_w2[(i0+i+1) * 240 + o], s1);
                s2 = fmaf(h1[i0+i+2], ff_w2[(i0+i+2) * 240 + o], s2);
                s3 = fmaf(h1[i0+i+3], ff_w2[(i0+i+3) * 240 + o], s3);
            }
            p2[seg][o] = (s0 + s1) + (s2 + s3);
        }
        __syncthreads();
        if (t < 240) h2[t] = tanhf(p2[0][t] + p2[1][t]);
        __syncthreads();

        if (t < 400) {           // layer 3: 200 outs, 2-way split-K (120 each)
            const int seg = t / 200, o = t - seg * 200, oc = half * 200 + o;
            const int i0 = seg * 120;
            float s0 = (seg == 0) ? ff_b3[oc] : 0.f, s1 = 0.f, s2 = 0.f, s3 = 0.f;
            #pragma unroll
            for (int i = 0; i < 120; i += 4) {
                s0 = fmaf(h2[i0+i+0], ff_w3[(i0+i+0) * 400 + oc], s0);
                s1 = fmaf(h2[i0+i+1], ff_w3[(i0+i+1) * 400 + oc], s1);
                s2 = fmaf(h2[i0+i+2], ff_w3[(i0+i+2) * 400 + oc], s2);
                s3 = fmaf(h2[i0+i+3], ff_w3[(i0+i+3) * 400 + oc], s3);
            }
            p3[seg][o] = (s0 + s1) + (s2 + s3);
        }
        __syncthreads();
        if (t < 200) integ[b * 400 + half * 200 + t] = p3[0][t] + p3[1][t];
    } else {
        // ---- kval: 16 points, thread = (f, slot, pt); 4-accum inner loop ----
        __shared__ float sw1[80], sb1[40], sw2[800], sb2[40], sw3[40], sb3[2];
        for (int i = t; i < 80;  i += 512) sw1[i] = k_w1[i];
        for (int i = t; i < 800; i += 512) sw2[i] = k_w2[i];
        if (t < 40) { sb1[t] = k_b1[t]; sb2[t] = k_b2[t]; sw3[t] = k_w3[t]; }
        if (t < 2)  sb3[t] = k_b3[t];
        __syncthreads();

        const int pid  = blockIdx.x - 128;   // 0..127, 16 points each
        const int f    = t >> 8;             // 0/1
        const int idx  = t & 255;
        const int slot = idx >> 4;           // 0..15 -> 4x4 window
        const int pt   = idx & 15;
        const int n    = pid * 16 + pt;
        const float2 g2 = ((const float2*)grid)[n];
        const float x = g2.x, y = g2.y;
        const int ilx = (int)ceilf((x - 0.15f) * 20.0f - 0.01f);
        const int ily = (int)ceilf((y - 0.15f) * 20.0f - 0.01f);
        const int ix = ilx + (slot >> 2);
        const int iy = ily + (slot & 3);

        float kv = 0.f;
        int k = 0;
        if (ix >= 0 && ix < 20 && iy >= 0 && iy < 20) {
            // replicate reference f32 arithmetic exactly (no fp-contract)
            const float gx = __fmul_rn((float)ix, 0.05f);
            const float gy = __fmul_rn((float)iy, 0.05f);
            const float lx = __fsub_rn(x, gx);
            const float ly = __fsub_rn(y, gy);
            if (lx >= 0.f && lx <= 0.15f && ly >= 0.f && ly <= 0.15f) {
                k = ix * 20 + iy;
                float hv[20];
                #pragma unroll
                for (int hh = 0; hh < 20; ++hh)
                    hv[hh] = fmaxf(0.f,
                        fmaf(lx, sw1[f * 40 + hh],
                        fmaf(ly, sw1[f * 40 + 20 + hh], sb1[f * 20 + hh])));
                float o = sb3[f];
                #pragma unroll
                for (int g = 0; g < 20; ++g) {
                    float s0 = sb2[f * 20 + g], s1 = 0.f, s2 = 0.f, s3 = 0.f;
                    #pragma unroll
                    for (int hh = 0; hh < 20; hh += 4) {
                        s0 = fmaf(hv[hh+0], sw2[f * 400 + (hh+0) * 20 + g], s0);
                        s1 = fmaf(hv[hh+1], sw2[f * 400 + (hh+1) * 20 + g], s1);
                        s2 = fmaf(hv[hh+2], sw2[f * 400 + (hh+2) * 20 + g], s2);
                        s3 = fmaf(hv[hh+3], sw2[f * 400 + (hh+3) * 20 + g], s3);
                    }
                    o = fmaf(fmaxf(0.f, (s0 + s1) + (s2 + s3)), sw3[f * 20 + g], o);
                }
                kv = o;
            }
        }
        float4* cell = &kvp[slot * NPTS + n];
        if (f == 0) { cell->x = kv; cell->z = __int_as_float(k); }
        else         cell->y = kv;          // k=0 with kv=0 is harmless
    }
}

// Kernel 2: block = (b, n-quarter); integ row in LDS; packed 16B kv loads.
__global__ __launch_bounds__(512) void k_field(
    const float* __restrict__ integ, const float4* __restrict__ kvp,
    float2* __restrict__ out)
{
    __shared__ float Li[KDIM];
    const int b = blockIdx.x >> 2;
    const int n = (blockIdx.x & 3) * 512 + threadIdx.x;
    if (threadIdx.x < KDIM / 4)
        ((f32x4*)Li)[threadIdx.x] = ((const f32x4*)(integ + b * KDIM))[threadIdx.x];
    __syncthreads();

    float a0 = 0.f, a1 = 0.f, c0 = 0.f, c1 = 0.f;
    #pragma unroll
    for (int j = 0; j < 16; j += 2) {
        const float4 cA = kvp[j * NPTS + n];
        const float4 cB = kvp[(j + 1) * NPTS + n];
        const float wA = Li[__float_as_int(cA.z)];
        const float wB = Li[__float_as_int(cB.z)];
        a0 = fmaf(cA.x, wA, a0); a1 = fmaf(cA.y, wA, a1);
        c0 = fmaf(cB.x, wB, c0); c1 = fmaf(cB.y, wB, c1);
    }
    out[b * NPTS + n] = make_float2(1.f / (1.f + __expf(-(a0 + c0))),
                                    1.f / (1.f + __expf(-(a1 + c1))));
}

extern "C" void kernel_launch(void* const* d_in, const int* in_sizes, int n_in,
                              void* d_out, int out_size, void* d_ws, size_t ws_size,
                              hipStream_t stream) {
    const float* weights = (const float*)d_in[0];
    const float* grid    = (const float*)d_in[1];
    const float* ff_w1   = (const float*)d_in[2];
    const float* ff_b1   = (const float*)d_in[3];
    const float* ff_w2   = (const float*)d_in[4];
    const float* ff_b2   = (const float*)d_in[5];
    const float* ff_w3   = (const float*)d_in[6];
    const float* ff_b3   = (const float*)d_in[7];
    const float* k_w1    = (const float*)d_in[8];
    const float* k_b1    = (const float*)d_in[9];
    const float* k_w2    = (const float*)d_in[10];
    const float* k_b2    = (const float*)d_in[11];
    const float* k_w3    = (const float*)d_in[12];
    const float* k_b3    = (const float*)d_in[13];

    float*  integ = (float*)d_ws;                       // 64*400 f32 (102400 B)
    float4* kvp   = (float4*)((char*)d_ws + 64 * KDIM * sizeof(float)); // 16*2048

    k_ff_and_kval<<<256, 512, 0, stream>>>(
        weights, grid, ff_w1, ff_b1, ff_w2, ff_b2, ff_w3, ff_b3,
        k_w1, k_b1, k_w2, k_b2, k_w3, k_b3,
        integ, kvp);

    k_field<<<256, 512, 0, stream>>>(integ, kvp, (float2*)d_out);
}

// Round 10
// 15.128 us; speedup vs baseline: 1.0306x; 1.0306x over previous
//
#include <hip/hip_runtime.h>
#include <math.h>

#define NPTS 2048
#define KDIM 400

// fast tanh: 1 - 2/(e^{2x}+1) on v_exp_f32/v_rcp_f32; saturates correctly.
__device__ __forceinline__ float fast_tanh(float x) {
    return 1.f - __fdividef(2.f, __expf(2.f * x) + 1.f);
}

// Kernel 1: blocks 0..127 = FF (2 per batch row, split-K); blocks 128..255 =
// kval, 16 points/block, thread = (f, slot, pt).
__global__ __launch_bounds__(512) void k_ff_and_kval(
    const float* __restrict__ weights, const float* __restrict__ grid,
    const float* __restrict__ ff_w1, const float* __restrict__ ff_b1,
    const float* __restrict__ ff_w2, const float* __restrict__ ff_b2,
    const float* __restrict__ ff_w3, const float* __restrict__ ff_b3,
    const float* __restrict__ k_w1, const float* __restrict__ k_b1,
    const float* __restrict__ k_w2, const float* __restrict__ k_b2,
    const float* __restrict__ k_w3, const float* __restrict__ k_b3,
    float* __restrict__ integ, float* __restrict__ kv0,
    float* __restrict__ kv1, int* __restrict__ kidx)
{
    const int t = threadIdx.x;
    if (blockIdx.x < 128) {
        // ---- FeedForward: block pair (b, half), split-K layers ----
        const int b = blockIdx.x >> 1, half = blockIdx.x & 1;
        __shared__ float wrow[256], h1[120], h2[240];
        __shared__ float p1[4][120], p2[2][240], p3[2][200];

        if (t < 256) wrow[t] = weights[b * 256 + t];
        __syncthreads();

        if (t < 480) {           // layer 1: 120 outs, 4-way split-K (64 each)
            const int seg = t / 120, o = t - seg * 120;
            float s = (seg == 0) ? ff_b1[o] : 0.f;
            const int i0 = seg * 64;
            #pragma unroll 16
            for (int i = 0; i < 64; ++i)
                s = fmaf(wrow[i0 + i], ff_w1[(i0 + i) * 120 + o], s);
            p1[seg][o] = s;
        }
        __syncthreads();
        if (t < 120) h1[t] = fast_tanh(p1[0][t] + p1[1][t] + p1[2][t] + p1[3][t]);
        __syncthreads();

        if (t < 480) {           // layer 2: 240 outs, 2-way split-K (60 each)
            const int seg = t / 240, o = t - seg * 240;
            float s = (seg == 0) ? ff_b2[o] : 0.f;
            const int i0 = seg * 60;
            #pragma unroll 15
            for (int i = 0; i < 60; ++i)
                s = fmaf(h1[i0 + i], ff_w2[(i0 + i) * 240 + o], s);
            p2[seg][o] = s;
        }
        __syncthreads();
        if (t < 240) h2[t] = fast_tanh(p2[0][t] + p2[1][t]);
        __syncthreads();

        if (t < 400) {           // layer 3: this block's 200 outs, 2-way split-K
            const int seg = t / 200, o = t - seg * 200, oc = half * 200 + o;
            float s = (seg == 0) ? ff_b3[oc] : 0.f;
            const int i0 = seg * 120;
            #pragma unroll 15
            for (int i = 0; i < 120; ++i)
                s = fmaf(h2[i0 + i], ff_w3[(i0 + i) * 400 + oc], s);
            p3[seg][o] = s;
        }
        __syncthreads();
        if (t < 200) integ[b * 400 + half * 200 + t] = p3[0][t] + p3[1][t];
    } else {
        // ---- kval: 16 points, thread = (f, slot, pt) ----
        __shared__ float sw1[80], sb1[40], sw2[800], sb2[40], sw3[40], sb3[2];
        for (int i = t; i < 80;  i += 512) sw1[i] = k_w1[i];
        for (int i = t; i < 800; i += 512) sw2[i] = k_w2[i];
        if (t < 40) { sb1[t] = k_b1[t]; sb2[t] = k_b2[t]; sw3[t] = k_w3[t]; }
        if (t < 2)  sb3[t] = k_b3[t];
        __syncthreads();

        const int pid  = blockIdx.x - 128;   // 0..127, 16 points each
        const int f    = t >> 8;             // 0/1
        const int idx  = t & 255;
        const int slot = idx >> 4;           // 0..15 -> 4x4 window
        const int pt   = idx & 15;
        const int n    = pid * 16 + pt;
        const float2 g2 = ((const float2*)grid)[n];
        const float x = g2.x, y = g2.y;
        const int ilx = (int)ceilf((x - 0.15f) * 20.0f - 0.01f);
        const int ily = (int)ceilf((y - 0.15f) * 20.0f - 0.01f);
        const int ix = ilx + (slot >> 2);
        const int iy = ily + (slot & 3);

        float kv = 0.f;
        int k = 0;
        if (ix >= 0 && ix < 20 && iy >= 0 && iy < 20) {
            // replicate reference f32 arithmetic exactly (no fp-contract)
            const float gx = __fmul_rn((float)ix, 0.05f);
            const float gy = __fmul_rn((float)iy, 0.05f);
            const float lx = __fsub_rn(x, gx);
            const float ly = __fsub_rn(y, gy);
            if (lx >= 0.f && lx <= 0.15f && ly >= 0.f && ly <= 0.15f) {
                k = ix * 20 + iy;
                float hv[20];
                #pragma unroll
                for (int hh = 0; hh < 20; ++hh)
                    hv[hh] = fmaxf(0.f,
                        fmaf(lx, sw1[f * 40 + hh],
                        fmaf(ly, sw1[f * 40 + 20 + hh], sb1[f * 20 + hh])));
                float o = sb3[f];
                #pragma unroll
                for (int g = 0; g < 20; ++g) {
                    float s = sb2[f * 20 + g];
                    #pragma unroll
                    for (int hh = 0; hh < 20; ++hh)
                        s = fmaf(hv[hh], sw2[f * 400 + hh * 20 + g], s);
                    o = fmaf(fmaxf(0.f, s), sw3[f * 20 + g], o);
                }
                kv = o;
            }
        }
        (f ? kv1 : kv0)[slot * NPTS + n] = kv;
        if (f == 0) kidx[slot * NPTS + n] = k;   // k=0 with kv=0 is harmless
    }
}

// Kernel 2: block = (b, n-quarter); integ row staged in LDS; 1 thread/(b,n).
__global__ __launch_bounds__(512) void k_field(
    const float* __restrict__ integ, const float* __restrict__ kv0,
    const float* __restrict__ kv1, const int* __restrict__ kidx,
    float2* __restrict__ out)
{
    __shared__ float Li[KDIM];
    const int b  = blockIdx.x >> 2;
    const int n  = (blockIdx.x & 3) * 512 + threadIdx.x;
    if (threadIdx.x < KDIM) Li[threadIdx.x] = integ[b * KDIM + threadIdx.x];
    __syncthreads();

    float a0 = 0.f, a1 = 0.f;
    #pragma unroll
    for (int j = 0; j < 16; ++j) {
        const float w = Li[kidx[j * NPTS + n]];
        a0 = fmaf(kv0[j * NPTS + n], w, a0);
        a1 = fmaf(kv1[j * NPTS + n], w, a1);
    }
    out[b * NPTS + n] = make_float2(__fdividef(1.f, 1.f + __expf(-a0)),
                                    __fdividef(1.f, 1.f + __expf(-a1)));
}

extern "C" void kernel_launch(void* const* d_in, const int* in_sizes, int n_in,
                              void* d_out, int out_size, void* d_ws, size_t ws_size,
                              hipStream_t stream) {
    const float* weights = (const float*)d_in[0];
    const float* grid    = (const float*)d_in[1];
    const float* ff_w1   = (const float*)d_in[2];
    const float* ff_b1   = (const float*)d_in[3];
    const float* ff_w2   = (const float*)d_in[4];
    const float* ff_b2   = (const float*)d_in[5];
    const float* ff_w3   = (const float*)d_in[6];
    const float* ff_b3   = (const float*)d_in[7];
    const float* k_w1    = (const float*)d_in[8];
    const float* k_b1    = (const float*)d_in[9];
    const float* k_w2    = (const float*)d_in[10];
    const float* k_b2    = (const float*)d_in[11];
    const float* k_w3    = (const float*)d_in[12];
    const float* k_b3    = (const float*)d_in[13];

    float* integ = (float*)d_ws;                 // 64*400
    float* kv0   = integ + 64 * KDIM;            // 16*2048
    float* kv1   = kv0 + 16 * NPTS;              // 16*2048
    int*   kidx  = (int*)(kv1 + 16 * NPTS);      // 16*2048

    k_ff_and_kval<<<256, 512, 0, stream>>>(
        weights, grid, ff_w1, ff_b1, ff_w2, ff_b2, ff_w3, ff_b3,
        k_w1, k_b1, k_w2, k_b2, k_w3, k_b3,
        integ, kv0, kv1, kidx);

    k_field<<<256, 512, 0, stream>>>(
        integ, kv0, kv1, kidx, (float2*)d_out);
}